// Round 4
// baseline (367.006 us; speedup 1.0000x reference)
//
#include <hip/hip_runtime.h>
#include <hip/hip_cooperative_groups.h>
#include <math.h>

namespace cg = cooperative_groups;

#define TOPK   9
#define NCLS   80
#define BATCH  8
#define NGT    128
#define NA     33600
#define OFF1   25600
#define OFF2   32000

// ---------- analytic anchors (exact vs reference fp32 construction) ----------
__device__ __forceinline__ void anchor_center(int a, float& cx, float& cy) {
    int j, gr, st;
    if (a < OFF1)      { j = a;        gr = 160; st = 8;  }
    else if (a < OFF2) { j = a - OFF1; gr = 80;  st = 16; }
    else               { j = a - OFF2; gr = 40;  st = 32; }
    int row = j / gr;
    int col = j - row * gr;
    cx = (float)(col * st + (st >> 1));
    cy = (float)(row * st + (st >> 1));
}
__device__ __forceinline__ float anchor_half(int a) {
    return (a < OFF1) ? 20.0f : (a < OFF2 ? 40.0f : 80.0f);
}
__device__ __forceinline__ float anchor_area(int a) {
    return (a < OFF1) ? 1600.0f : (a < OFF2 ? 6400.0f : 25600.0f);
}

// IOU with reference's exact expression order: inter / ((area_g + area_a) - inter + 1e-9)
__device__ __forceinline__ float iou_ga(float gx1, float gy1, float gx2, float gy2,
                                        float ax1, float ay1, float ax2, float ay2,
                                        float area_a) {
    float ltx = fmaxf(gx1, ax1), lty = fmaxf(gy1, ay1);
    float rbx = fminf(gx2, ax2), rby = fminf(gy2, ay2);
    float w = fmaxf(__fsub_rn(rbx, ltx), 0.0f);
    float h = fmaxf(__fsub_rn(rby, lty), 0.0f);
    float inter = __fmul_rn(w, h);
    float ag = __fmul_rn(__fsub_rn(gx2, gx1), __fsub_rn(gy2, gy1));
    float denom = __fadd_rn(__fsub_rn(__fadd_rn(ag, area_a), inter), 1e-9f);
    return inter / denom;
}

// lexicographic (dist, idx) "less" — matches lax.top_k tie-break (lower idx wins)
__device__ __forceinline__ bool dless(float da, int ia, float db, int ib) {
    return (da < db) || (da == db && ia < ib);
}

// ---- single cooperative kernel: zero claims -> window+claims -> resolve+write ----
// Phase-1 window sufficiency proof (round-2 journal): clamped 5x5 around the
// nearest grid cell always contains the per-level top-9 (strict distance gap in
// every clamp case). All decision arithmetic identical to the absmax-0.0
// validated kernels of rounds 1-3.
__launch_bounds__(256)
__global__ void atss_fused_kernel(const float* __restrict__ gt_bboxes,
                                  const int* __restrict__ gt_labels,
                                  const float* __restrict__ pad_mask,
                                  const int* __restrict__ bg_index_p,
                                  int* __restrict__ claim_cnt,
                                  int* __restrict__ claim_gt,
                                  float* __restrict__ out_labels,
                                  float* __restrict__ out_bboxes,
                                  float* __restrict__ out_scores) {
    cg::grid_group grid = cg::this_grid();
    const int tid = threadIdx.x;
    const int t   = blockIdx.x * 256 + tid;   // grid = B*NA/256 blocks, covers all anchors

    __shared__ float sd[75];
    __shared__ int   sj[75];
    __shared__ float sx[75], sy[75];
    __shared__ float cand_iou[27];
    __shared__ int   cand_a[27];
    __shared__ int   cand_ok[27];
    __shared__ float thr;
    __shared__ int   slbl[256];

    // ---- phase 0: zero the claim table (d_ws is poisoned before every call) ----
    claim_cnt[t] = 0;
    grid.sync();

    // ---- phase 1: per-(b,g) window top-9 + threshold + claims (blocks 0..1023) ----
    if (blockIdx.x < BATCH * NGT) {
        const int b = blockIdx.x >> 7;
        const int g = blockIdx.x & 127;
        if (pad_mask[b * NGT + g] > 0.0f) {   // block-uniform
            const float4 gtb = *reinterpret_cast<const float4*>(gt_bboxes + (size_t)(b * NGT + g) * 4);
            const float gcx = __fmul_rn(__fadd_rn(gtb.x, gtb.z), 0.5f);
            const float gcy = __fmul_rn(__fadd_rn(gtb.y, gtb.w), 0.5f);

            const int l  = tid / 25;
            const int c  = tid % 25;
            const int GR = (l == 0) ? 160 : (l == 1 ? 80 : 40);
            const int ST = 8 << l;

            if (tid < 75) {
                const float inv = (l == 0) ? 0.125f : (l == 1 ? 0.0625f : 0.03125f);
                int ix = (int)floorf(__fmul_rn(gcx, inv));
                int iy = (int)floorf(__fmul_rn(gcy, inv));
                ix = min(max(ix, 0), GR - 1);
                iy = min(max(iy, 0), GR - 1);
                const int wx = min(max(ix - 2, 0), GR - 5);
                const int wy = min(max(iy - 2, 0), GR - 5);
                const int col = wx + c % 5;
                const int row = wy + c / 5;
                const float ax = (float)(col * ST + (ST >> 1));
                const float ay = (float)(row * ST + (ST >> 1));
                const float dx = __fsub_rn(gcx, ax);
                const float dy = __fsub_rn(gcy, ay);
                sd[tid] = __fsqrt_rn(__fadd_rn(__fmul_rn(dx, dx), __fmul_rn(dy, dy)));
                sj[tid] = row * GR + col;
                sx[tid] = ax;
                sy[tid] = ay;
            }
            __syncthreads();
            if (tid < 75) {
                const int base = l * 25;
                const float d = sd[tid];
                const int   j = sj[tid];
                int rank = 0;
#pragma unroll
                for (int c2 = 0; c2 < 25; ++c2) {
                    rank += dless(sd[base + c2], sj[base + c2], d, j) ? 1 : 0;
                }
                if (rank < TOPK) {
                    const int offs = (l == 0) ? 0 : (l == 1 ? OFF1 : OFF2);
                    const float hf = (l == 0) ? 20.0f : (l == 1 ? 40.0f : 80.0f);
                    const float aa = (l == 0) ? 1600.0f : (l == 1 ? 6400.0f : 25600.0f);
                    const float acx = sx[tid], acy = sy[tid];
                    const int slot = l * TOPK + rank;
                    cand_iou[slot] = iou_ga(gtb.x, gtb.y, gtb.z, gtb.w,
                                            acx - hf, acy - hf, acx + hf, acy + hf, aa);
                    cand_a[slot] = j + offs;
                    const float l_ = __fsub_rn(acx, gtb.x);
                    const float t_ = __fsub_rn(acy, gtb.y);
                    const float r_ = __fsub_rn(gtb.z, acx);
                    const float b_ = __fsub_rn(gtb.w, acy);
                    const float mn = fminf(fminf(l_, t_), fminf(r_, b_));
                    cand_ok[slot] = (mn > 1e-9f) ? 1 : 0;
                }
            }
            __syncthreads();
            if (tid == 0) {  // serial order matches validated rounds (bit-exact)
                float sum = 0.0f;
#pragma unroll
                for (int k = 0; k < 3 * TOPK; ++k) sum = __fadd_rn(sum, cand_iou[k]);
                const float mean = sum / 27.0f;
                float ss = 0.0f;
#pragma unroll
                for (int k = 0; k < 3 * TOPK; ++k) {
                    const float dd = __fsub_rn(cand_iou[k], mean);
                    ss = __fadd_rn(ss, __fmul_rn(dd, dd));
                }
                thr = __fadd_rn(mean, __fsqrt_rn(ss / 26.0f));  // ddof=1
            }
            __syncthreads();
            if (tid < 3 * TOPK) {
                if (cand_ok[tid] && cand_iou[tid] > thr) {
                    const int a = cand_a[tid];
                    atomicAdd(&claim_cnt[b * NA + a], 1);       // device-scope
                    claim_gt[b * NA + a] = g;                   // race-free when cnt==1
                }
            }
        }
    }
    __threadfence();   // make claims visible device-wide before the grid barrier
    grid.sync();

    // ---- phase 2: per-(b,a) resolve + labels + bboxes + fused one-hot scores ----
    {
        const int b = t / NA;
        const int a = t - b * NA;

        const int cnt = claim_cnt[t];
        int  gidx = 0;
        bool pos  = false;
        if (cnt == 1) {
            gidx = claim_gt[t];
            pos = true;
        } else if (cnt > 1) {
            // reference: column replaced by is_max_iou = argmax_g iou (first max wins)
            float acx, acy;
            anchor_center(a, acx, acy);
            const float hf = anchor_half(a);
            const float aa = anchor_area(a);
            const float ax1 = acx - hf, ay1 = acy - hf, ax2 = acx + hf, ay2 = acy + hf;
            float best = -1.0f;
            int bestg = 0;
            for (int gg = 0; gg < NGT; ++gg) {
                const float4 gb = *reinterpret_cast<const float4*>(gt_bboxes + (size_t)(b * NGT + gg) * 4);
                const float iou = iou_ga(gb.x, gb.y, gb.z, gb.w, ax1, ay1, ax2, ay2, aa);
                if (iou > best) { best = iou; bestg = gg; }
            }
            gidx = bestg;
            pos = true;
        }

        // assigned_bboxes: gathered even for background (gt index 0)
        const float4 bb = *reinterpret_cast<const float4*>(gt_bboxes + (size_t)(b * NGT + gidx) * 4);
        reinterpret_cast<float4*>(out_bboxes)[t] = bb;

        const int lbl = pos ? gt_labels[b * NGT + gidx] : bg_index_p[0];
        out_labels[t] = (float)lbl;

        // fused one-hot scores: block-local labels in LDS, lane-linear float4 stores
        slbl[tid] = pos ? lbl : NCLS;   // NCLS (=bg) never matches cls in [0,80)
        __syncthreads();
        const size_t sbase = (size_t)blockIdx.x * 256 * NCLS;
#pragma unroll
        for (int i = 0; i < 20; ++i) {
            const int off  = i * 1024 + tid * 4;      // 0..20476, multiple of 4
            const int aoff = off / 80;                // anchor within block
            const int cls  = off - aoff * 80;
            const int lb   = slbl[aoff];
            float4 v;
            v.x = (cls     == lb) ? 1.0f : 0.0f;
            v.y = (cls + 1 == lb) ? 1.0f : 0.0f;
            v.z = (cls + 2 == lb) ? 1.0f : 0.0f;
            v.w = (cls + 3 == lb) ? 1.0f : 0.0f;
            *reinterpret_cast<float4*>(out_scores + sbase + off) = v;
        }
    }
}

extern "C" void kernel_launch(void* const* d_in, const int* in_sizes, int n_in,
                              void* d_out, int out_size, void* d_ws, size_t ws_size,
                              hipStream_t stream) {
    const float* anchors   = (const float*)d_in[0];  // unused: anchors are analytic (exact)
    const int*   gt_labels = (const int*)d_in[1];
    const float* gt_bboxes = (const float*)d_in[2];
    const float* pad_mask  = (const float*)d_in[3];
    const int*   bg_index  = (const int*)d_in[4];
    (void)anchors; (void)in_sizes; (void)n_in; (void)out_size; (void)ws_size;

    float* out        = (float*)d_out;
    float* out_labels = out;                          // B*NA
    float* out_bboxes = out + (size_t)BATCH * NA;     // B*NA*4
    float* out_scores = out + (size_t)BATCH * NA * 5; // B*NA*80

    int* claim_cnt = (int*)d_ws;              // B*NA ints
    int* claim_gt  = claim_cnt + BATCH * NA;  // B*NA ints

    void* args[] = {
        (void*)&gt_bboxes, (void*)&gt_labels, (void*)&pad_mask, (void*)&bg_index,
        (void*)&claim_cnt, (void*)&claim_gt,
        (void*)&out_labels, (void*)&out_bboxes, (void*)&out_scores,
    };
    hipLaunchCooperativeKernel((void*)atss_fused_kernel,
                               dim3((BATCH * NA) / 256), dim3(256),
                               args, 0, stream);
}

// Round 6
// 246.423 us; speedup vs baseline: 1.4893x; 1.4893x over previous
//
#include <hip/hip_runtime.h>
#include <math.h>

#define TOPK   9
#define NCLS   80
#define BATCH  8
#define NGT    128
#define NA     33600
#define OFF1   25600
#define OFF2   32000
#define CHUNK  320
#define NCHUNK 105   // NA / CHUNK exactly

// ---------- analytic anchors (exact vs reference fp32 construction) ----------
__device__ __forceinline__ void anchor_center(int a, float& cx, float& cy) {
    int j, gr, st;
    if (a < OFF1)      { j = a;        gr = 160; st = 8;  }
    else if (a < OFF2) { j = a - OFF1; gr = 80;  st = 16; }
    else               { j = a - OFF2; gr = 40;  st = 32; }
    int row = j / gr;
    int col = j - row * gr;
    cx = (float)(col * st + (st >> 1));
    cy = (float)(row * st + (st >> 1));
}
__device__ __forceinline__ float anchor_half(int a) {
    return (a < OFF1) ? 20.0f : (a < OFF2 ? 40.0f : 80.0f);
}
__device__ __forceinline__ float anchor_area(int a) {
    return (a < OFF1) ? 1600.0f : (a < OFF2 ? 6400.0f : 25600.0f);
}

// IOU with reference's exact expression order: inter / ((area_g + area_a) - inter + 1e-9)
__device__ __forceinline__ float iou_ga(float gx1, float gy1, float gx2, float gy2,
                                        float ax1, float ay1, float ax2, float ay2,
                                        float area_a) {
    float ltx = fmaxf(gx1, ax1), lty = fmaxf(gy1, ay1);
    float rbx = fminf(gx2, ax2), rby = fminf(gy2, ay2);
    float w = fmaxf(__fsub_rn(rbx, ltx), 0.0f);
    float h = fmaxf(__fsub_rn(rby, lty), 0.0f);
    float inter = __fmul_rn(w, h);
    float ag = __fmul_rn(__fsub_rn(gx2, gx1), __fsub_rn(gy2, gy1));
    float denom = __fadd_rn(__fsub_rn(__fadd_rn(ag, area_a), inter), 1e-9f);
    return inter / denom;
}

// lexicographic (dist, idx) "less" — matches lax.top_k tie-break (lower idx wins)
__device__ __forceinline__ bool dless(float da, int ia, float db, int ib) {
    return (da < db) || (da == db && ia < ib);
}

// ---- single ordinary kernel: block = (batch, 320-anchor chunk). Each block
// redundantly recomputes ALL 128 gts' ATSS decisions (cheap, deterministic,
// identical across blocks) and keeps claims in LDS — no global claim table,
// no memset, no grid sync, one dispatch.
// Window sufficiency proof (round-2 journal): clamped 5x5 around the nearest
// grid cell always contains the per-level top-9 (strict distance gap in every
// clamp case). All decision arithmetic verbatim from the absmax-0.0 kernels.
__launch_bounds__(256, 4)
__global__ void atss_onepass_kernel(const float* __restrict__ gt_bboxes,
                                    const int* __restrict__ gt_labels,
                                    const float* __restrict__ pad_mask,
                                    const int* __restrict__ bg_index_p,
                                    float* __restrict__ out_labels,
                                    float* __restrict__ out_bboxes,
                                    float* __restrict__ out_scores) {
    const int tid   = threadIdx.x;
    const int b     = blockIdx.x / NCHUNK;
    const int chunk = blockIdx.x - b * NCHUNK;
    const int abase = chunk * CHUNK;

    __shared__ float4 sBox[NGT];        // 2 KB
    __shared__ int    sLbl[NGT];        // 0.5 KB
    __shared__ float  sPad[NGT];        // 0.5 KB
    __shared__ float  cIou[NGT * 27];   // 13.5 KB
    __shared__ int    cPack[NGT * 27];  // 13.5 KB  (anchor id | ok<<20)
    __shared__ float  sThr[NGT];        // 0.5 KB
    __shared__ int    sCnt[CHUNK];      // 1.25 KB
    __shared__ int    sG[CHUNK];        // 1.25 KB
    __shared__ int    sOutL[CHUNK];     // 1.25 KB   -> ~34.3 KB total, 4 blocks/CU

    // ---- load batch gt data + zero claim table ----
    if (tid < NGT) {
        sBox[tid] = *reinterpret_cast<const float4*>(gt_bboxes + (size_t)(b * NGT + tid) * 4);
        sLbl[tid] = gt_labels[b * NGT + tid];
        sPad[tid] = pad_mask[b * NGT + tid];
    }
    for (int s = tid; s < CHUNK; s += 256) sCnt[s] = 0;
    __syncthreads();

    // ---- stage A: 384 (gt,level) units — window top-9 + candidate iou/ok ----
    for (int u = tid; u < 3 * NGT; u += 256) {
        const int l = u >> 7;          // level 0..2
        const int g = u & (NGT - 1);
        if (sPad[g] <= 0.0f) continue;

        const int   GR   = (l == 0) ? 160 : (l == 1 ? 80 : 40);
        const int   ST   = 8 << l;
        const float inv  = (l == 0) ? 0.125f : (l == 1 ? 0.0625f : 0.03125f);
        const int   offs = (l == 0) ? 0 : (l == 1 ? OFF1 : OFF2);
        const float hf   = (l == 0) ? 20.0f : (l == 1 ? 40.0f : 80.0f);
        const float aa   = (l == 0) ? 1600.0f : (l == 1 ? 6400.0f : 25600.0f);

        const float4 gb  = sBox[g];
        const float  gcx = __fmul_rn(__fadd_rn(gb.x, gb.z), 0.5f);
        const float  gcy = __fmul_rn(__fadd_rn(gb.y, gb.w), 0.5f);

        int ix = (int)floorf(__fmul_rn(gcx, inv));
        int iy = (int)floorf(__fmul_rn(gcy, inv));
        ix = min(max(ix, 0), GR - 1);
        iy = min(max(iy, 0), GR - 1);
        const int wx = min(max(ix - 2, 0), GR - 5);
        const int wy = min(max(iy - 2, 0), GR - 5);

        // register insertion top-9 over the 25 window points, j ascending.
        // Stable strict-less insertion == rank-by-count ordering (validated).
        float bd[TOPK]; int bj[TOPK]; float bx[TOPK]; float by[TOPK];
#pragma unroll
        for (int k = 0; k < TOPK; ++k) { bd[k] = INFINITY; bj[k] = 0x7FFFFFFF; bx[k] = 0.f; by[k] = 0.f; }
        for (int r = 0; r < 5; ++r) {
            for (int c = 0; c < 5; ++c) {
                const int col = wx + c, row = wy + r;
                const float ax = (float)(col * ST + (ST >> 1));
                const float ay = (float)(row * ST + (ST >> 1));
                const float dx = __fsub_rn(gcx, ax);
                const float dy = __fsub_rn(gcy, ay);
                const float d  = __fsqrt_rn(__fadd_rn(__fmul_rn(dx, dx), __fmul_rn(dy, dy)));
                const int   j  = row * GR + col;
                if (dless(d, j, bd[TOPK - 1], bj[TOPK - 1])) {
                    bd[TOPK - 1] = d; bj[TOPK - 1] = j; bx[TOPK - 1] = ax; by[TOPK - 1] = ay;
#pragma unroll
                    for (int k = TOPK - 1; k > 0; --k) {
                        if (dless(bd[k], bj[k], bd[k - 1], bj[k - 1])) {
                            float t0 = bd[k]; bd[k] = bd[k - 1]; bd[k - 1] = t0;
                            int   t1 = bj[k]; bj[k] = bj[k - 1]; bj[k - 1] = t1;
                            float t2 = bx[k]; bx[k] = bx[k - 1]; bx[k - 1] = t2;
                            float t3 = by[k]; by[k] = by[k - 1]; by[k - 1] = t3;
                        }
                    }
                }
            }
        }
#pragma unroll
        for (int k = 0; k < TOPK; ++k) {
            const float acx = bx[k], acy = by[k];
            const float iou = iou_ga(gb.x, gb.y, gb.z, gb.w,
                                     acx - hf, acy - hf, acx + hf, acy + hf, aa);
            const float l_ = __fsub_rn(acx, gb.x);
            const float t_ = __fsub_rn(acy, gb.y);
            const float r_ = __fsub_rn(gb.z, acx);
            const float b_ = __fsub_rn(gb.w, acy);
            const float mn = fminf(fminf(l_, t_), fminf(r_, b_));
            const int   ok = (mn > 1e-9f) ? 1 : 0;
            const int   slot = g * 27 + l * TOPK + k;
            cIou[slot]  = iou;
            cPack[slot] = (bj[k] + offs) | (ok << 20);
        }
    }
    __syncthreads();

    // ---- stage B: per-gt serial mean/std threshold (bit-exact validated order) ----
    if (tid < NGT && sPad[tid] > 0.0f) {
        const float* cv = &cIou[tid * 27];
        float sum = 0.0f;
#pragma unroll
        for (int k = 0; k < 27; ++k) sum = __fadd_rn(sum, cv[k]);
        const float mean = sum / 27.0f;
        float ss = 0.0f;
#pragma unroll
        for (int k = 0; k < 27; ++k) {
            const float dd = __fsub_rn(cv[k], mean);
            ss = __fadd_rn(ss, __fmul_rn(dd, dd));
        }
        sThr[tid] = __fadd_rn(mean, __fsqrt_rn(ss / 26.0f));   // ddof=1
    }
    __syncthreads();

    // ---- stage C: decisions -> LDS claims for this block's anchor range ----
    for (int e = tid; e < NGT * 27; e += 256) {
        const int g = e / 27;
        if (sPad[g] <= 0.0f) continue;
        const int pk = cPack[e];
        if ((pk >> 20) & 1) {
            if (cIou[e] > sThr[g]) {
                const int a = pk & 0xFFFFF;
                const int s = a - abase;
                if (s >= 0 && s < CHUNK) {
                    atomicAdd(&sCnt[s], 1);
                    sG[s] = g;   // benign race: value only used when cnt==1
                }
            }
        }
    }
    __syncthreads();

    // ---- stage D: resolve + labels + bboxes ----
    const int bg = bg_index_p[0];
    for (int s = tid; s < CHUNK; s += 256) {
        const int a   = abase + s;
        const int cnt = sCnt[s];
        int  gidx = 0;
        bool pos  = false;
        if (cnt == 1) {
            gidx = sG[s];
            pos = true;
        } else if (cnt > 1) {
            // reference: column replaced by is_max_iou = argmax_g iou (first max wins)
            float acx, acy;
            anchor_center(a, acx, acy);
            const float hf2 = anchor_half(a);
            const float aa2 = anchor_area(a);
            const float ax1 = acx - hf2, ay1 = acy - hf2, ax2 = acx + hf2, ay2 = acy + hf2;
            float best = -1.0f;
            int bestg = 0;
            for (int gg = 0; gg < NGT; ++gg) {
                const float4 gbb = sBox[gg];
                const float iou = iou_ga(gbb.x, gbb.y, gbb.z, gbb.w, ax1, ay1, ax2, ay2, aa2);
                if (iou > best) { best = iou; bestg = gg; }
            }
            gidx = bestg;
            pos = true;
        }

        const int t = b * NA + a;
        // assigned_bboxes: gathered even for background (gt index 0)
        reinterpret_cast<float4*>(out_bboxes)[t] = sBox[gidx];
        const int lbl = pos ? sLbl[gidx] : bg;
        out_labels[t] = (float)lbl;
        sOutL[s] = pos ? lbl : NCLS;   // NCLS (=bg) never matches cls in [0,80)
    }
    __syncthreads();

    // ---- stage E: one-hot scores, lane-linear float4 stores (validated pattern) ----
    const size_t sbase = (size_t)(b * NA + abase) * NCLS;   // block span is contiguous
#pragma unroll
    for (int i = 0; i < 25; ++i) {                          // 25*1024 = 320*80 exactly
        const int off  = i * 1024 + tid * 4;
        const int aoff = off / 80;                          // anchor within chunk
        const int cls  = off - aoff * 80;
        const int lb   = sOutL[aoff];
        float4 v;
        v.x = (cls     == lb) ? 1.0f : 0.0f;
        v.y = (cls + 1 == lb) ? 1.0f : 0.0f;
        v.z = (cls + 2 == lb) ? 1.0f : 0.0f;
        v.w = (cls + 3 == lb) ? 1.0f : 0.0f;
        *reinterpret_cast<float4*>(out_scores + sbase + off) = v;
    }
}

extern "C" void kernel_launch(void* const* d_in, const int* in_sizes, int n_in,
                              void* d_out, int out_size, void* d_ws, size_t ws_size,
                              hipStream_t stream) {
    const float* anchors   = (const float*)d_in[0];  // unused: anchors are analytic (exact)
    const int*   gt_labels = (const int*)d_in[1];
    const float* gt_bboxes = (const float*)d_in[2];
    const float* pad_mask  = (const float*)d_in[3];
    const int*   bg_index  = (const int*)d_in[4];
    (void)anchors; (void)in_sizes; (void)n_in; (void)out_size; (void)d_ws; (void)ws_size;

    float* out        = (float*)d_out;
    float* out_labels = out;                          // B*NA
    float* out_bboxes = out + (size_t)BATCH * NA;     // B*NA*4
    float* out_scores = out + (size_t)BATCH * NA * 5; // B*NA*80

    atss_onepass_kernel<<<BATCH * NCHUNK, 256, 0, stream>>>(
        gt_bboxes, gt_labels, pad_mask, bg_index,
        out_labels, out_bboxes, out_scores);
}

// Round 17
// 144.839 us; speedup vs baseline: 2.5339x; 1.7014x over previous
//
#include <hip/hip_runtime.h>
#include <math.h>

#define TOPK   9
#define NCLS   80
#define BATCH  8
#define NGT    128
#define NA     33600
#define OFF1   25600
#define OFF2   32000
#define CHUNK  320
#define NCHUNK 105   // NA / CHUNK exactly; chunks 0..79 lvl0, 80..99 lvl1, 100..104 lvl2
#define NSEL_TILE 64

// ---------- analytic anchors (exact vs reference fp32 construction) ----------
__device__ __forceinline__ void anchor_center(int a, float& cx, float& cy) {
    int j, gr, st;
    if (a < OFF1)      { j = a;        gr = 160; st = 8;  }
    else if (a < OFF2) { j = a - OFF1; gr = 80;  st = 16; }
    else               { j = a - OFF2; gr = 40;  st = 32; }
    int row = j / gr;
    int col = j - row * gr;
    cx = (float)(col * st + (st >> 1));
    cy = (float)(row * st + (st >> 1));
}
__device__ __forceinline__ float anchor_half(int a) {
    return (a < OFF1) ? 20.0f : (a < OFF2 ? 40.0f : 80.0f);
}
__device__ __forceinline__ float anchor_area(int a) {
    return (a < OFF1) ? 1600.0f : (a < OFF2 ? 6400.0f : 25600.0f);
}

// IOU with reference's exact expression order: inter / ((area_g + area_a) - inter + 1e-9)
__device__ __forceinline__ float iou_ga(float gx1, float gy1, float gx2, float gy2,
                                        float ax1, float ay1, float ax2, float ay2,
                                        float area_a) {
    float ltx = fmaxf(gx1, ax1), lty = fmaxf(gy1, ay1);
    float rbx = fminf(gx2, ax2), rby = fminf(gy2, ay2);
    float w = fmaxf(__fsub_rn(rbx, ltx), 0.0f);
    float h = fmaxf(__fsub_rn(rby, lty), 0.0f);
    float inter = __fmul_rn(w, h);
    float ag = __fmul_rn(__fsub_rn(gx2, gx1), __fsub_rn(gy2, gy1));
    float denom = __fadd_rn(__fsub_rn(__fadd_rn(ag, area_a), inter), 1e-9f);
    return inter / denom;
}

// lexicographic (dist, idx) "less" — matches lax.top_k tie-break (lower idx wins)
// p = (row<<8)|col is strictly monotone with j = row*GR+col (col < GR <= 160 < 256),
// so comparing p is identical to comparing j.
__device__ __forceinline__ bool dless(float da, int ia, float db, int ib) {
    return (da < db) || (da == db && ia < ib);
}

// ---- single kernel: block = (batch, 320-anchor chunk); chunk lies in ONE level.
// Per block: cheap filter (which gts' block-level 5x5 windows touch my rows),
// then full 27-candidate ATSS decision only for those gts; claims in LDS.
// Top-9 via 9 selection passes (k-th smallest in (d,idx) lex order) — zero
// register arrays (round-6 spill fix), provably the same sorted top-9 as the
// validated insertion/rank kernels. Window sufficiency proof: round-2 journal.
// All decision arithmetic verbatim from the absmax-0.0 validated kernels.
__launch_bounds__(256, 2)
__global__ void atss_onepass_kernel(const float* __restrict__ gt_bboxes,
                                    const int* __restrict__ gt_labels,
                                    const float* __restrict__ pad_mask,
                                    const int* __restrict__ bg_index_p,
                                    float* __restrict__ out_labels,
                                    float* __restrict__ out_bboxes,
                                    float* __restrict__ out_scores) {
    const int tid   = threadIdx.x;
    const int b     = blockIdx.x / NCHUNK;
    const int chunk = blockIdx.x - b * NCHUNK;

    // block-level geometry (chunk -> level, row band)
    int lvl, GR, r0, nrows, offs;
    if (chunk < 80)       { lvl = 0; GR = 160; offs = 0;    r0 = chunk * 2;         nrows = 2; }
    else if (chunk < 100) { lvl = 1; GR = 80;  offs = OFF1; r0 = (chunk - 80) * 4;  nrows = 4; }
    else                  { lvl = 2; GR = 40;  offs = OFF2; r0 = (chunk - 100) * 8; nrows = 8; }
    const float invB = (lvl == 0) ? 0.125f : (lvl == 1 ? 0.0625f : 0.03125f);
    const int abase = offs + r0 * GR;   // == chunk*CHUNK

    __shared__ float4 sBox[NGT];               // 2 KB
    __shared__ int    sLbl[NGT];               // 0.5 KB
    __shared__ float  sPad[NGT];               // 0.5 KB
    __shared__ int    selG[NGT];               // 0.5 KB
    __shared__ float  tIou[NSEL_TILE][27];     // 6.75 KB
    __shared__ int    tPack[NSEL_TILE][27];    // 6.75 KB
    __shared__ int    sCnt[CHUNK];             // 1.25 KB
    __shared__ int    sG[CHUNK];               // 1.25 KB
    __shared__ int    sOutL[CHUNK];            // 1.25 KB
    __shared__ int    nSel;                    // ~20.8 KB total

    // ---- load batch gt data, zero claim table ----
    if (tid < NGT) {
        sBox[tid] = *reinterpret_cast<const float4*>(gt_bboxes + (size_t)(b * NGT + tid) * 4);
        sLbl[tid] = gt_labels[b * NGT + tid];
        sPad[tid] = pad_mask[b * NGT + tid];
    }
    if (tid == 0) nSel = 0;
    for (int s = tid; s < CHUNK; s += 256) sCnt[s] = 0;
    __syncthreads();

    // ---- filter: gts whose block-level window rows intersect [r0, r0+nrows) ----
    if (tid < NGT && sPad[tid] > 0.0f) {
        const float4 gb = sBox[tid];
        const float gcy = __fmul_rn(__fadd_rn(gb.y, gb.w), 0.5f);
        int iy = (int)floorf(__fmul_rn(gcy, invB));
        iy = min(max(iy, 0), GR - 1);
        const int wy = min(max(iy - 2, 0), GR - 5);
        if (wy < r0 + nrows && wy + 5 > r0) {
            const int p = atomicAdd(&nSel, 1);
            selG[p] = tid;
        }
    }
    __syncthreads();
    const int nSelL = nSel;

    // ---- decision tiles: <=64 selected gts at a time ----
    for (int t0 = 0; t0 < nSelL; t0 += NSEL_TILE) {
        const int nt = min(NSEL_TILE, nSelL - t0);

        // units: (sel, level) — full window top-9 + 9 candidate iou/ok each
        if (tid < 3 * nt) {
            const int s = tid / 3;
            const int l = tid - 3 * s;
            const int g = selG[t0 + s];

            const int   GRl  = (l == 0) ? 160 : (l == 1 ? 80 : 40);
            const int   STl  = 8 << l;
            const int   offl = (l == 0) ? 0 : (l == 1 ? OFF1 : OFF2);
            const float invl = (l == 0) ? 0.125f : (l == 1 ? 0.0625f : 0.03125f);
            const float hfl  = (l == 0) ? 20.0f : (l == 1 ? 40.0f : 80.0f);
            const float aal  = (l == 0) ? 1600.0f : (l == 1 ? 6400.0f : 25600.0f);

            const float4 gb  = sBox[g];
            const float  gcx = __fmul_rn(__fadd_rn(gb.x, gb.z), 0.5f);
            const float  gcy = __fmul_rn(__fadd_rn(gb.y, gb.w), 0.5f);

            int ix = (int)floorf(__fmul_rn(gcx, invl));
            int iy = (int)floorf(__fmul_rn(gcy, invl));
            ix = min(max(ix, 0), GRl - 1);
            iy = min(max(iy, 0), GRl - 1);
            const int wx = min(max(ix - 2, 0), GRl - 5);
            const int wy = min(max(iy - 2, 0), GRl - 5);

            // 9 selection passes: k-th smallest (d, p) in lex order (scalar state only)
            float dl_ = -INFINITY;
            int   pl_ = -1;
            for (int k = 0; k < TOPK; ++k) {
                float db = INFINITY;
                int   pb = 0x7FFFFFFF;
                for (int r = 0; r < 5; ++r) {
                    for (int c = 0; c < 5; ++c) {
                        const int row = wy + r, col = wx + c;
                        const float ax = (float)(col * STl + (STl >> 1));
                        const float ay = (float)(row * STl + (STl >> 1));
                        const float dx = __fsub_rn(gcx, ax);
                        const float dy = __fsub_rn(gcy, ay);
                        const float d  = __fsqrt_rn(__fadd_rn(__fmul_rn(dx, dx), __fmul_rn(dy, dy)));
                        const int   p  = (row << 8) | col;
                        if (dless(dl_, pl_, d, p) && dless(d, p, db, pb)) { db = d; pb = p; }
                    }
                }
                dl_ = db; pl_ = pb;

                const int row = pb >> 8, col = pb & 255;
                const float acx = (float)(col * STl + (STl >> 1));
                const float acy = (float)(row * STl + (STl >> 1));
                const float iou = iou_ga(gb.x, gb.y, gb.z, gb.w,
                                         acx - hfl, acy - hfl, acx + hfl, acy + hfl, aal);
                const float l_ = __fsub_rn(acx, gb.x);
                const float t_ = __fsub_rn(acy, gb.y);
                const float r_ = __fsub_rn(gb.z, acx);
                const float b_ = __fsub_rn(gb.w, acy);
                const float mn = fminf(fminf(l_, t_), fminf(r_, b_));
                const int   ok = (mn > 1e-9f) ? 1 : 0;
                const int   inchunk = (l == lvl && row >= r0 && row < r0 + nrows) ? 1 : 0;
                const int   aGlob = row * GRl + col + offl;
                tIou[s][l * TOPK + k]  = iou;
                tPack[s][l * TOPK + k] = aGlob | (ok << 20) | (inchunk << 21);
            }
        }
        __syncthreads();

        // threshold (bit-exact serial order) + claims into LDS
        if (tid < nt) {
            const int s = tid;
            const int g = selG[t0 + s];
            float sum = 0.0f;
#pragma unroll
            for (int k = 0; k < 27; ++k) sum = __fadd_rn(sum, tIou[s][k]);
            const float mean = sum / 27.0f;
            float ss = 0.0f;
#pragma unroll
            for (int k = 0; k < 27; ++k) {
                const float dd = __fsub_rn(tIou[s][k], mean);
                ss = __fadd_rn(ss, __fmul_rn(dd, dd));
            }
            const float thr = __fadd_rn(mean, __fsqrt_rn(ss / 26.0f));  // ddof=1
#pragma unroll
            for (int k = 0; k < 27; ++k) {
                const int pk = tPack[s][k];
                if (((pk >> 20) & 1) && ((pk >> 21) & 1) && tIou[s][k] > thr) {
                    const int sidx = (pk & 0xFFFFF) - abase;
                    atomicAdd(&sCnt[sidx], 1);
                    sG[sidx] = g;   // benign race: value only used when cnt==1
                }
            }
        }
        __syncthreads();
    }

    // ---- resolve + labels + bboxes ----
    const int bg = bg_index_p[0];
    for (int s = tid; s < CHUNK; s += 256) {
        const int a   = abase + s;
        const int cnt = sCnt[s];
        int  gidx = 0;
        bool pos  = false;
        if (cnt == 1) {
            gidx = sG[s];
            pos = true;
        } else if (cnt > 1) {
            // reference: column replaced by is_max_iou = argmax_g iou (first max wins)
            float acx, acy;
            anchor_center(a, acx, acy);
            const float hf2 = anchor_half(a);
            const float aa2 = anchor_area(a);
            const float ax1 = acx - hf2, ay1 = acy - hf2, ax2 = acx + hf2, ay2 = acy + hf2;
            float best = -1.0f;
            int bestg = 0;
            for (int gg = 0; gg < NGT; ++gg) {
                const float4 gbb = sBox[gg];
                const float iou = iou_ga(gbb.x, gbb.y, gbb.z, gbb.w, ax1, ay1, ax2, ay2, aa2);
                if (iou > best) { best = iou; bestg = gg; }
            }
            gidx = bestg;
            pos = true;
        }

        const int t = b * NA + a;
        // assigned_bboxes: gathered even for background (gt index 0)
        reinterpret_cast<float4*>(out_bboxes)[t] = sBox[gidx];
        const int lbl = pos ? sLbl[gidx] : bg;
        out_labels[t] = (float)lbl;
        sOutL[s] = pos ? lbl : NCLS;   // NCLS (=bg) never matches cls in [0,80)
    }
    __syncthreads();

    // ---- one-hot scores: lane-linear float4 stores (validated pattern) ----
    const size_t sbase = (size_t)(b * NA + abase) * NCLS;   // block span contiguous
#pragma unroll
    for (int i = 0; i < 25; ++i) {                          // 25*1024 = 320*80 exactly
        const int off  = i * 1024 + tid * 4;
        const int aoff = off / 80;                          // anchor within chunk
        const int cls  = off - aoff * 80;
        const int lb   = sOutL[aoff];
        float4 v;
        v.x = (cls     == lb) ? 1.0f : 0.0f;
        v.y = (cls + 1 == lb) ? 1.0f : 0.0f;
        v.z = (cls + 2 == lb) ? 1.0f : 0.0f;
        v.w = (cls + 3 == lb) ? 1.0f : 0.0f;
        *reinterpret_cast<float4*>(out_scores + sbase + off) = v;
    }
}

extern "C" void kernel_launch(void* const* d_in, const int* in_sizes, int n_in,
                              void* d_out, int out_size, void* d_ws, size_t ws_size,
                              hipStream_t stream) {
    const float* anchors   = (const float*)d_in[0];  // unused: anchors are analytic (exact)
    const int*   gt_labels = (const int*)d_in[1];
    const float* gt_bboxes = (const float*)d_in[2];
    const float* pad_mask  = (const float*)d_in[3];
    const int*   bg_index  = (const int*)d_in[4];
    (void)anchors; (void)in_sizes; (void)n_in; (void)out_size; (void)d_ws; (void)ws_size;

    float* out        = (float*)d_out;
    float* out_labels = out;                          // B*NA
    float* out_bboxes = out + (size_t)BATCH * NA;     // B*NA*4
    float* out_scores = out + (size_t)BATCH * NA * 5; // B*NA*80

    atss_onepass_kernel<<<BATCH * NCHUNK, 256, 0, stream>>>(
        gt_bboxes, gt_labels, pad_mask, bg_index,
        out_labels, out_bboxes, out_scores);
}